// Round 2
// baseline (403.455 us; speedup 1.0000x reference)
//
#include <hip/hip_runtime.h>

#define NN 50000
#define NE 800000
#define NG 64

// ---------------- degree count ----------------
__global__ __launch_bounds__(256) void k_deg(const int* __restrict__ dst, int* __restrict__ degcnt) {
    int e = blockIdx.x * 256 + threadIdx.x;
    if (e < NE) atomicAdd(&degcnt[dst[e]], 1);
}

__global__ __launch_bounds__(256) void k_dinv(const int* __restrict__ degcnt, float* __restrict__ dinv) {
    int i = blockIdx.x * 256 + threadIdx.x;
    if (i < NN) dinv[i] = (float)(1.0 / sqrt((double)degcnt[i] + 1.0));
}

// ---------------- prefix scan (3 stages) ----------------
__global__ __launch_bounds__(1024) void k_scan1(const int* __restrict__ cnt, int* __restrict__ row_ptr,
                                                int* __restrict__ blk_sums) {
    __shared__ int s[1024];
    const int tid = threadIdx.x;
    const int i = blockIdx.x * 1024 + tid;
    int v = (i < NN) ? cnt[i] : 0;
    s[tid] = v;
    __syncthreads();
    for (int off = 1; off < 1024; off <<= 1) {
        int t = (tid >= off) ? s[tid - off] : 0;
        __syncthreads();
        s[tid] += t;
        __syncthreads();
    }
    if (i < NN) row_ptr[i] = s[tid] - v;     // exclusive
    if (tid == 1023) blk_sums[blockIdx.x] = s[1023];
}

__global__ __launch_bounds__(64) void k_scan2(int* __restrict__ blk_sums, int nb) {
    int l = threadIdx.x;
    int v = (l < nb) ? blk_sums[l] : 0;
    int incl = v;
    for (int off = 1; off < 64; off <<= 1) {
        int t = __shfl_up(incl, off, 64);
        if (l >= off) incl += t;
    }
    if (l < nb) blk_sums[l] = incl - v;      // exclusive block offsets
}

__global__ __launch_bounds__(1024) void k_scan3(int* __restrict__ row_ptr, const int* __restrict__ blk_sums) {
    int i = blockIdx.x * 1024 + threadIdx.x;
    if (i < NN) row_ptr[i] += blk_sums[blockIdx.x];
    if (i == 0) row_ptr[NN] = NE;
}

// ---------------- CSR fill ----------------
__global__ __launch_bounds__(256) void k_fill(const int* __restrict__ ei, const float* __restrict__ dinv,
                                              const int* __restrict__ row_ptr, int* __restrict__ cursor,
                                              int* __restrict__ csr_src, float* __restrict__ csr_norm) {
    int e = blockIdx.x * 256 + threadIdx.x;
    if (e >= NE) return;
    int s = ei[e];
    int d = ei[NE + e];
    int pos = row_ptr[d] + atomicAdd(&cursor[d], 1);
    csr_src[pos] = s;
    csr_norm[pos] = dinv[s] * dinv[d];
}

// ---------------- fp32 GEMM: C[M x DO] = A[M x 128] @ W[128 x DO] ----------------
template <int DO, int TN>
__global__ __launch_bounds__(256) void k_gemm(const float* __restrict__ A, const float* __restrict__ W,
                                              float* __restrict__ C, int M) {
    constexpr int KK = 32;
    constexpr int BM = 128;
    constexpr int XPAD = 132;
    __shared__ float Ws[KK][DO];
    __shared__ float Xs[KK][XPAD];
    const int tid = threadIdx.x;
    const int rg = tid & 15;   // 16 row groups x 8 rows = 128 rows
    const int cg = tid >> 4;   // 16 col groups x TN cols
    const int row0 = blockIdx.x * BM;

    float acc[8][TN];
#pragma unroll
    for (int i = 0; i < 8; ++i)
#pragma unroll
        for (int j = 0; j < TN; ++j) acc[i][j] = 0.0f;

    for (int kk = 0; kk < 128; kk += KK) {
        // stage W chunk [KK][DO]
        constexpr int WF4 = KK * DO / 4;
        for (int it = tid; it < WF4; it += 256) {
            int k = it / (DO / 4);
            int c4 = it % (DO / 4);
            float4 v = *(const float4*)&W[(size_t)(kk + k) * DO + c4 * 4];
            *(float4*)&Ws[k][c4 * 4] = v;
        }
        // stage X^T chunk [KK][BM]
        for (int it = tid; it < BM * KK / 4; it += 256) {
            int r = it >> 3;     // 0..127
            int q = it & 7;      // k-quad 0..7
            int grow = row0 + r;
            float4 v = make_float4(0.f, 0.f, 0.f, 0.f);
            if (grow < M) v = *(const float4*)&A[(size_t)grow * 128 + kk + q * 4];
            Xs[q * 4 + 0][r] = v.x;
            Xs[q * 4 + 1][r] = v.y;
            Xs[q * 4 + 2][r] = v.z;
            Xs[q * 4 + 3][r] = v.w;
        }
        __syncthreads();
#pragma unroll
        for (int k = 0; k < KK; ++k) {
            float xf[8];
            *(float4*)&xf[0] = *(const float4*)&Xs[k][rg * 8];
            *(float4*)&xf[4] = *(const float4*)&Xs[k][rg * 8 + 4];
            float wf[TN];
#pragma unroll
            for (int j = 0; j < TN; j += 4) *(float4*)&wf[j] = *(const float4*)&Ws[k][cg * TN + j];
#pragma unroll
            for (int i = 0; i < 8; ++i)
#pragma unroll
                for (int j = 0; j < TN; ++j) acc[i][j] = fmaf(xf[i], wf[j], acc[i][j]);
        }
        __syncthreads();
    }
#pragma unroll
    for (int i = 0; i < 8; ++i) {
        int r = row0 + rg * 8 + i;
        if (r < M) {
#pragma unroll
            for (int j = 0; j < TN; j += 4) {
                *(float4*)&C[(size_t)r * DO + cg * TN + j] =
                    make_float4(acc[i][j], acc[i][j + 1], acc[i][j + 2], acc[i][j + 3]);
            }
        }
    }
}

// ---------------- aggregation: out = A_norm @ T + dinv^2*T + b (+relu), f64 accum ----------------
template <int D, bool RELU>
__global__ __launch_bounds__(256) void k_agg(const float* __restrict__ T, const float* __restrict__ bias,
                                             const float* __restrict__ dinv, const int* __restrict__ row_ptr,
                                             const int* __restrict__ csr_src, const float* __restrict__ csr_norm,
                                             float* __restrict__ out) {
    constexpr int G = D / 4;        // lanes per node
    constexpr int NPB = 256 / G;    // nodes per block
    const int tid = threadIdx.x;
    const int lane = tid % G;
    const int grp = tid / G;
    const int n = blockIdx.x * NPB + grp;
    if (n >= NN) return;

    double a0 = 0.0, a1 = 0.0, a2 = 0.0, a3 = 0.0;
    const int beg = row_ptr[n];
    const int end = row_ptr[n + 1];
    int e = beg;
    // 4-way unrolled: 4 independent gathers in flight per step
    for (; e + 4 <= end; e += 4) {
        const int s0 = csr_src[e + 0], s1 = csr_src[e + 1], s2 = csr_src[e + 2], s3 = csr_src[e + 3];
        const float w0 = csr_norm[e + 0], w1 = csr_norm[e + 1], w2 = csr_norm[e + 2], w3 = csr_norm[e + 3];
        const float4 v0 = *(const float4*)&T[(size_t)s0 * D + lane * 4];
        const float4 v1 = *(const float4*)&T[(size_t)s1 * D + lane * 4];
        const float4 v2 = *(const float4*)&T[(size_t)s2 * D + lane * 4];
        const float4 v3 = *(const float4*)&T[(size_t)s3 * D + lane * 4];
        a0 += (double)w0 * v0.x + (double)w1 * v1.x + (double)w2 * v2.x + (double)w3 * v3.x;
        a1 += (double)w0 * v0.y + (double)w1 * v1.y + (double)w2 * v2.y + (double)w3 * v3.y;
        a2 += (double)w0 * v0.z + (double)w1 * v1.z + (double)w2 * v2.z + (double)w3 * v3.z;
        a3 += (double)w0 * v0.w + (double)w1 * v1.w + (double)w2 * v2.w + (double)w3 * v3.w;
    }
    for (; e < end; ++e) {
        const int s = csr_src[e];
        const float w = csr_norm[e];
        const float4 v = *(const float4*)&T[(size_t)s * D + lane * 4];
        a0 += (double)w * v.x;
        a1 += (double)w * v.y;
        a2 += (double)w * v.z;
        a3 += (double)w * v.w;
    }
    // self-loop
    {
        const double di = (double)dinv[n];
        const double w = di * di;
        const float4 v = *(const float4*)&T[(size_t)n * D + lane * 4];
        a0 += w * v.x;
        a1 += w * v.y;
        a2 += w * v.z;
        a3 += w * v.w;
    }
    // bias
    const float4 b = *(const float4*)&bias[lane * 4];
    a0 += b.x; a1 += b.y; a2 += b.z; a3 += b.w;
    float4 r;
    r.x = (float)a0; r.y = (float)a1; r.z = (float)a2; r.w = (float)a3;
    if (RELU) {
        r.x = fmaxf(r.x, 0.f);
        r.y = fmaxf(r.y, 0.f);
        r.z = fmaxf(r.z, 0.f);
        r.w = fmaxf(r.w, 0.f);
    }
    *(float4*)&out[(size_t)n * D + lane * 4] = r;
}

// ---------------- mean pool (batch sorted), f64 accum ----------------
__global__ __launch_bounds__(256) void k_pool(const float* __restrict__ h, const int* __restrict__ batch,
                                              double* __restrict__ sums, int* __restrict__ cnts) {
    const int NB = 256;
    const int n0 = blockIdx.x * NB;
    const int d = threadIdx.x & 63;
    const int sub = threadIdx.x >> 6;
    double acc = 0.0;
    int cnt = 0;
    int cur = -1;
    for (int i = sub; i < NB; i += 4) {
        int n = n0 + i;
        if (n >= NN) break;
        int g = batch[n];
        if (g != cur) {
            if (cur >= 0) {
                atomicAdd(&sums[cur * 64 + d], acc);
                if (d == 0) atomicAdd(&cnts[cur], cnt);
            }
            cur = g;
            acc = 0.0;
            cnt = 0;
        }
        acc += (double)h[(size_t)n * 64 + d];
        cnt++;
    }
    if (cur >= 0) {
        atomicAdd(&sums[cur * 64 + d], acc);
        if (d == 0) atomicAdd(&cnts[cur], cnt);
    }
}

__global__ __launch_bounds__(256) void k_final(const double* __restrict__ sums, const int* __restrict__ cnts,
                                               float* __restrict__ out) {
    int i = blockIdx.x * 256 + threadIdx.x;
    if (i >= NG * 64) return;
    int g = i >> 6;
    double c = (double)max(cnts[g], 1);
    out[i] = (float)(sums[i] / c);
}

extern "C" void kernel_launch(void* const* d_in, const int* in_sizes, int n_in,
                              void* d_out, int out_size, void* d_ws, size_t ws_size,
                              hipStream_t stream) {
    (void)in_sizes; (void)n_in; (void)out_size; (void)ws_size;
    const float* x     = (const float*)d_in[0];
    const int*   ei    = (const int*)d_in[1];
    const int*   batch = (const int*)d_in[2];
    const float* W1    = (const float*)d_in[3];
    const float* b1    = (const float*)d_in[4];
    const float* W2    = (const float*)d_in[5];
    const float* b2    = (const float*)d_in[6];
    const float* W3    = (const float*)d_in[7];
    const float* b3    = (const float*)d_in[8];
    float* out = (float*)d_out;

    // workspace layout: small metadata first, big h-buffers last
    char* w = (char*)d_ws;
    // zeroed region (single memset): degcnt | cursor | pool_sums(double) | pool_cnt
    char*  zbase = w;
    int*    degcnt = (int*)w;           w += (size_t)NN * 4;
    int*    cursor = (int*)w;           w += (size_t)NN * 4;
    double* psums  = (double*)w;        w += (size_t)NG * 64 * 8;
    int*    pcnts  = (int*)w;           w += 256;               // NG*4 padded to 16B
    size_t zbytes = (size_t)(w - zbase);
    float* dinv     = (float*)w;        w += (size_t)NN * 4;
    int*   row_ptr  = (int*)w;          w += (size_t)(NN + 4) * 4;
    int*   blk_sums = (int*)w;          w += 64 * 4;
    int*   csr_src  = (int*)w;          w += (size_t)NE * 4;
    float* csr_norm = (float*)w;        w += (size_t)NE * 4;
    float* bufT = (float*)w;            w += (size_t)NN * 128 * 4;
    float* bufA = (float*)w;            w += (size_t)NN * 128 * 4;

    hipMemsetAsync(zbase, 0, zbytes, stream);

    const int nb_scan = (NN + 1023) / 1024;   // 49
    k_deg<<<(NE + 255) / 256, 256, 0, stream>>>(ei + NE, degcnt);
    k_dinv<<<(NN + 255) / 256, 256, 0, stream>>>(degcnt, dinv);
    k_scan1<<<nb_scan, 1024, 0, stream>>>(degcnt, row_ptr, blk_sums);
    k_scan2<<<1, 64, 0, stream>>>(blk_sums, nb_scan);
    k_scan3<<<nb_scan, 1024, 0, stream>>>(row_ptr, blk_sums);
    k_fill<<<(NE + 255) / 256, 256, 0, stream>>>(ei, dinv, row_ptr, cursor, csr_src, csr_norm);

    const int gemm_grid = (NN + 127) / 128;   // 391
    // layer 1
    k_gemm<128, 8><<<gemm_grid, 256, 0, stream>>>(x, W1, bufT, NN);
    k_agg<128, true><<<(NN + 7) / 8, 256, 0, stream>>>(bufT, b1, dinv, row_ptr, csr_src, csr_norm, bufA);
    // layer 2
    k_gemm<128, 8><<<gemm_grid, 256, 0, stream>>>(bufA, W2, bufT, NN);
    k_agg<128, true><<<(NN + 7) / 8, 256, 0, stream>>>(bufT, b2, dinv, row_ptr, csr_src, csr_norm, bufA);
    // layer 3 (no relu, D_OUT=64)
    k_gemm<64, 4><<<gemm_grid, 256, 0, stream>>>(bufA, W3, bufT, NN);
    k_agg<64, false><<<(NN + 15) / 16, 256, 0, stream>>>(bufT, b3, dinv, row_ptr, csr_src, csr_norm, bufA);
    // pool
    k_pool<<<(NN + 255) / 256, 256, 0, stream>>>(bufA, batch, psums, pcnts);
    k_final<<<(NG * 64 + 255) / 256, 256, 0, stream>>>(psums, pcnts, out);
}

// Round 3
// 331.091 us; speedup vs baseline: 1.2186x; 1.2186x over previous
//
#include <hip/hip_runtime.h>

#define NN 50000
#define NE 800000
#define NG 64

// bf16 helpers (RTNE)
__device__ __forceinline__ unsigned short f2bf(float f) {
    unsigned int u = __float_as_uint(f);
    u = (u + 0x7FFFu + ((u >> 16) & 1u)) >> 16;
    return (unsigned short)u;
}
__device__ __forceinline__ float bf2f(unsigned short h) {
    return __uint_as_float((unsigned int)h << 16);
}

// ---------------- degree count ----------------
__global__ __launch_bounds__(256) void k_deg(const int* __restrict__ dst, int* __restrict__ degcnt) {
    int e = blockIdx.x * 256 + threadIdx.x;
    if (e < NE) atomicAdd(&degcnt[dst[e]], 1);
}

__global__ __launch_bounds__(256) void k_dinv(const int* __restrict__ degcnt, float* __restrict__ dinv) {
    int i = blockIdx.x * 256 + threadIdx.x;
    if (i < NN) dinv[i] = (float)(1.0 / sqrt((double)degcnt[i] + 1.0));
}

// ---------------- prefix scan (3 stages) ----------------
__global__ __launch_bounds__(1024) void k_scan1(const int* __restrict__ cnt, int* __restrict__ row_ptr,
                                                int* __restrict__ blk_sums) {
    __shared__ int s[1024];
    const int tid = threadIdx.x;
    const int i = blockIdx.x * 1024 + tid;
    int v = (i < NN) ? cnt[i] : 0;
    s[tid] = v;
    __syncthreads();
    for (int off = 1; off < 1024; off <<= 1) {
        int t = (tid >= off) ? s[tid - off] : 0;
        __syncthreads();
        s[tid] += t;
        __syncthreads();
    }
    if (i < NN) row_ptr[i] = s[tid] - v;     // exclusive
    if (tid == 1023) blk_sums[blockIdx.x] = s[1023];
}

__global__ __launch_bounds__(64) void k_scan2(int* __restrict__ blk_sums, int nb) {
    int l = threadIdx.x;
    int v = (l < nb) ? blk_sums[l] : 0;
    int incl = v;
    for (int off = 1; off < 64; off <<= 1) {
        int t = __shfl_up(incl, off, 64);
        if (l >= off) incl += t;
    }
    if (l < nb) blk_sums[l] = incl - v;      // exclusive block offsets
}

__global__ __launch_bounds__(1024) void k_scan3(int* __restrict__ row_ptr, const int* __restrict__ blk_sums) {
    int i = blockIdx.x * 1024 + threadIdx.x;
    if (i < NN) row_ptr[i] += blk_sums[blockIdx.x];
    if (i == 0) row_ptr[NN] = NE;
}

// ---------------- CSR fill ----------------
__global__ __launch_bounds__(256) void k_fill(const int* __restrict__ ei, const float* __restrict__ dinv,
                                              const int* __restrict__ row_ptr, int* __restrict__ cursor,
                                              int* __restrict__ csr_src, float* __restrict__ csr_norm) {
    int e = blockIdx.x * 256 + threadIdx.x;
    if (e >= NE) return;
    int s = ei[e];
    int d = ei[NE + e];
    int pos = row_ptr[d] + atomicAdd(&cursor[d], 1);
    csr_src[pos] = s;
    csr_norm[pos] = dinv[s] * dinv[d];
}

// ---------------- fp32 GEMM: C[M x DO] = A[M x 128] @ W[128 x DO], bf16 output ----------------
template <int DO, int TN>
__global__ __launch_bounds__(256) void k_gemm(const float* __restrict__ A, const float* __restrict__ W,
                                              unsigned short* __restrict__ C, int M) {
    constexpr int KK = 32;
    constexpr int BM = 128;
    constexpr int XPAD = 132;
    __shared__ float Ws[KK][DO];
    __shared__ float Xs[KK][XPAD];
    const int tid = threadIdx.x;
    const int rg = tid & 15;   // 16 row groups x 8 rows = 128 rows
    const int cg = tid >> 4;   // 16 col groups x TN cols
    const int row0 = blockIdx.x * BM;

    float acc[8][TN];
#pragma unroll
    for (int i = 0; i < 8; ++i)
#pragma unroll
        for (int j = 0; j < TN; ++j) acc[i][j] = 0.0f;

    for (int kk = 0; kk < 128; kk += KK) {
        // stage W chunk [KK][DO]
        constexpr int WF4 = KK * DO / 4;
        for (int it = tid; it < WF4; it += 256) {
            int k = it / (DO / 4);
            int c4 = it % (DO / 4);
            float4 v = *(const float4*)&W[(size_t)(kk + k) * DO + c4 * 4];
            *(float4*)&Ws[k][c4 * 4] = v;
        }
        // stage X^T chunk [KK][BM]
        for (int it = tid; it < BM * KK / 4; it += 256) {
            int r = it >> 3;     // 0..127
            int q = it & 7;      // k-quad 0..7
            int grow = row0 + r;
            float4 v = make_float4(0.f, 0.f, 0.f, 0.f);
            if (grow < M) v = *(const float4*)&A[(size_t)grow * 128 + kk + q * 4];
            Xs[q * 4 + 0][r] = v.x;
            Xs[q * 4 + 1][r] = v.y;
            Xs[q * 4 + 2][r] = v.z;
            Xs[q * 4 + 3][r] = v.w;
        }
        __syncthreads();
#pragma unroll
        for (int k = 0; k < KK; ++k) {
            float xf[8];
            *(float4*)&xf[0] = *(const float4*)&Xs[k][rg * 8];
            *(float4*)&xf[4] = *(const float4*)&Xs[k][rg * 8 + 4];
            float wf[TN];
#pragma unroll
            for (int j = 0; j < TN; j += 4) *(float4*)&wf[j] = *(const float4*)&Ws[k][cg * TN + j];
#pragma unroll
            for (int i = 0; i < 8; ++i)
#pragma unroll
                for (int j = 0; j < TN; ++j) acc[i][j] = fmaf(xf[i], wf[j], acc[i][j]);
        }
        __syncthreads();
    }
    // epilogue: pack TN bf16 (TN*2 bytes) per row and store
#pragma unroll
    for (int i = 0; i < 8; ++i) {
        int r = row0 + rg * 8 + i;
        if (r < M) {
            unsigned int pk[TN / 2];
#pragma unroll
            for (int j = 0; j < TN; j += 2) {
                pk[j / 2] = (unsigned int)f2bf(acc[i][j]) | ((unsigned int)f2bf(acc[i][j + 1]) << 16);
            }
            unsigned short* dst = &C[(size_t)r * DO + cg * TN];
            if (TN == 8) {
                *(uint4*)dst = make_uint4(pk[0], pk[1], pk[2], pk[3 % (TN / 2)]);
            } else {
                *(uint2*)dst = make_uint2(pk[0], pk[1 % (TN / 2)]);
            }
        }
    }
}

// ---------------- aggregation: out = A_norm @ T + dinv^2*T + b (+relu), bf16 T, f64 accum ----------------
template <int D, bool RELU>
__global__ __launch_bounds__(256) void k_agg(const unsigned short* __restrict__ T, const float* __restrict__ bias,
                                             const float* __restrict__ dinv, const int* __restrict__ row_ptr,
                                             const int* __restrict__ csr_src, const float* __restrict__ csr_norm,
                                             float* __restrict__ out) {
    constexpr int G = D / 4;        // lanes per node, each lane owns 4 features (8 B bf16)
    constexpr int NPB = 256 / G;    // nodes per block
    const int tid = threadIdx.x;
    const int lane = tid % G;
    const int grp = tid / G;
    const int n = blockIdx.x * NPB + grp;
    if (n >= NN) return;

    double a0 = 0.0, a1 = 0.0, a2 = 0.0, a3 = 0.0;
    const int beg = row_ptr[n];
    const int end = row_ptr[n + 1];
    int e = beg;
    // 4-way unrolled: 4 independent gathers in flight per step
    for (; e + 4 <= end; e += 4) {
        const int s0 = csr_src[e + 0], s1 = csr_src[e + 1], s2 = csr_src[e + 2], s3 = csr_src[e + 3];
        const float w0 = csr_norm[e + 0], w1 = csr_norm[e + 1], w2 = csr_norm[e + 2], w3 = csr_norm[e + 3];
        const ushort4 v0 = *(const ushort4*)&T[(size_t)s0 * D + lane * 4];
        const ushort4 v1 = *(const ushort4*)&T[(size_t)s1 * D + lane * 4];
        const ushort4 v2 = *(const ushort4*)&T[(size_t)s2 * D + lane * 4];
        const ushort4 v3 = *(const ushort4*)&T[(size_t)s3 * D + lane * 4];
        a0 += (double)w0 * bf2f(v0.x) + (double)w1 * bf2f(v1.x) + (double)w2 * bf2f(v2.x) + (double)w3 * bf2f(v3.x);
        a1 += (double)w0 * bf2f(v0.y) + (double)w1 * bf2f(v1.y) + (double)w2 * bf2f(v2.y) + (double)w3 * bf2f(v3.y);
        a2 += (double)w0 * bf2f(v0.z) + (double)w1 * bf2f(v1.z) + (double)w2 * bf2f(v2.z) + (double)w3 * bf2f(v3.z);
        a3 += (double)w0 * bf2f(v0.w) + (double)w1 * bf2f(v1.w) + (double)w2 * bf2f(v2.w) + (double)w3 * bf2f(v3.w);
    }
    for (; e < end; ++e) {
        const int s = csr_src[e];
        const float w = csr_norm[e];
        const ushort4 v = *(const ushort4*)&T[(size_t)s * D + lane * 4];
        a0 += (double)w * bf2f(v.x);
        a1 += (double)w * bf2f(v.y);
        a2 += (double)w * bf2f(v.z);
        a3 += (double)w * bf2f(v.w);
    }
    // self-loop
    {
        const double di = (double)dinv[n];
        const double w = di * di;
        const ushort4 v = *(const ushort4*)&T[(size_t)n * D + lane * 4];
        a0 += w * bf2f(v.x);
        a1 += w * bf2f(v.y);
        a2 += w * bf2f(v.z);
        a3 += w * bf2f(v.w);
    }
    // bias
    const float4 b = *(const float4*)&bias[lane * 4];
    a0 += b.x; a1 += b.y; a2 += b.z; a3 += b.w;
    float4 r;
    r.x = (float)a0; r.y = (float)a1; r.z = (float)a2; r.w = (float)a3;
    if (RELU) {
        r.x = fmaxf(r.x, 0.f);
        r.y = fmaxf(r.y, 0.f);
        r.z = fmaxf(r.z, 0.f);
        r.w = fmaxf(r.w, 0.f);
    }
    *(float4*)&out[(size_t)n * D + lane * 4] = r;
}

// ---------------- mean pool (batch sorted), f64 accum ----------------
__global__ __launch_bounds__(256) void k_pool(const float* __restrict__ h, const int* __restrict__ batch,
                                              double* __restrict__ sums, int* __restrict__ cnts) {
    const int NB = 256;
    const int n0 = blockIdx.x * NB;
    const int d = threadIdx.x & 63;
    const int sub = threadIdx.x >> 6;
    double acc = 0.0;
    int cnt = 0;
    int cur = -1;
    for (int i = sub; i < NB; i += 4) {
        int n = n0 + i;
        if (n >= NN) break;
        int g = batch[n];
        if (g != cur) {
            if (cur >= 0) {
                atomicAdd(&sums[cur * 64 + d], acc);
                if (d == 0) atomicAdd(&cnts[cur], cnt);
            }
            cur = g;
            acc = 0.0;
            cnt = 0;
        }
        acc += (double)h[(size_t)n * 64 + d];
        cnt++;
    }
    if (cur >= 0) {
        atomicAdd(&sums[cur * 64 + d], acc);
        if (d == 0) atomicAdd(&cnts[cur], cnt);
    }
}

__global__ __launch_bounds__(256) void k_final(const double* __restrict__ sums, const int* __restrict__ cnts,
                                               float* __restrict__ out) {
    int i = blockIdx.x * 256 + threadIdx.x;
    if (i >= NG * 64) return;
    int g = i >> 6;
    double c = (double)max(cnts[g], 1);
    out[i] = (float)(sums[i] / c);
}

extern "C" void kernel_launch(void* const* d_in, const int* in_sizes, int n_in,
                              void* d_out, int out_size, void* d_ws, size_t ws_size,
                              hipStream_t stream) {
    (void)in_sizes; (void)n_in; (void)out_size; (void)ws_size;
    const float* x     = (const float*)d_in[0];
    const int*   ei    = (const int*)d_in[1];
    const int*   batch = (const int*)d_in[2];
    const float* W1    = (const float*)d_in[3];
    const float* b1    = (const float*)d_in[4];
    const float* W2    = (const float*)d_in[5];
    const float* b2    = (const float*)d_in[6];
    const float* W3    = (const float*)d_in[7];
    const float* b3    = (const float*)d_in[8];
    float* out = (float*)d_out;

    // workspace layout: small metadata first, big h-buffers last
    char* w = (char*)d_ws;
    // zeroed region (single memset): degcnt | cursor | pool_sums(double) | pool_cnt
    char*  zbase = w;
    int*    degcnt = (int*)w;           w += (size_t)NN * 4;
    int*    cursor = (int*)w;           w += (size_t)NN * 4;
    double* psums  = (double*)w;        w += (size_t)NG * 64 * 8;
    int*    pcnts  = (int*)w;           w += 256;               // NG*4 padded to 16B
    size_t zbytes = (size_t)(w - zbase);
    float* dinv     = (float*)w;        w += (size_t)NN * 4;
    int*   row_ptr  = (int*)w;          w += (size_t)(NN + 4) * 4;
    int*   blk_sums = (int*)w;          w += 64 * 4;
    int*   csr_src  = (int*)w;          w += (size_t)NE * 4;
    float* csr_norm = (float*)w;        w += (size_t)NE * 4;
    unsigned short* bufT = (unsigned short*)w;  w += (size_t)NN * 128 * 2;  // bf16 gather target
    float* bufA = (float*)w;            w += (size_t)NN * 128 * 4;          // fp32 GEMM input

    hipMemsetAsync(zbase, 0, zbytes, stream);

    const int nb_scan = (NN + 1023) / 1024;   // 49
    k_deg<<<(NE + 255) / 256, 256, 0, stream>>>(ei + NE, degcnt);
    k_dinv<<<(NN + 255) / 256, 256, 0, stream>>>(degcnt, dinv);
    k_scan1<<<nb_scan, 1024, 0, stream>>>(degcnt, row_ptr, blk_sums);
    k_scan2<<<1, 64, 0, stream>>>(blk_sums, nb_scan);
    k_scan3<<<nb_scan, 1024, 0, stream>>>(row_ptr, blk_sums);
    k_fill<<<(NE + 255) / 256, 256, 0, stream>>>(ei, dinv, row_ptr, cursor, csr_src, csr_norm);

    const int gemm_grid = (NN + 127) / 128;   // 391
    // layer 1
    k_gemm<128, 8><<<gemm_grid, 256, 0, stream>>>(x, W1, bufT, NN);
    k_agg<128, true><<<(NN + 7) / 8, 256, 0, stream>>>(bufT, b1, dinv, row_ptr, csr_src, csr_norm, bufA);
    // layer 2
    k_gemm<128, 8><<<gemm_grid, 256, 0, stream>>>(bufA, W2, bufT, NN);
    k_agg<128, true><<<(NN + 7) / 8, 256, 0, stream>>>(bufT, b2, dinv, row_ptr, csr_src, csr_norm, bufA);
    // layer 3 (no relu, D_OUT=64)
    k_gemm<64, 4><<<gemm_grid, 256, 0, stream>>>(bufA, W3, bufT, NN);
    k_agg<64, false><<<(NN + 15) / 16, 256, 0, stream>>>(bufT, b3, dinv, row_ptr, csr_src, csr_norm, bufA);
    // pool
    k_pool<<<(NN + 255) / 256, 256, 0, stream>>>(bufA, batch, psums, pcnts);
    k_final<<<(NG * 64 + 255) / 256, 256, 0, stream>>>(psums, pcnts, out);
}

// Round 6
// 297.204 us; speedup vs baseline: 1.3575x; 1.1140x over previous
//
#include <hip/hip_runtime.h>

#define NN 50000
#define NE 800000
#define NG 64

typedef short short8 __attribute__((ext_vector_type(8)));
typedef float f32x4 __attribute__((ext_vector_type(4)));

// bf16 helpers (RTNE)
__device__ __forceinline__ unsigned short f2bf(float f) {
    unsigned int u = __float_as_uint(f);
    u = (u + 0x7FFFu + ((u >> 16) & 1u)) >> 16;
    return (unsigned short)u;
}
__device__ __forceinline__ float bf2f(unsigned short h) {
    return __uint_as_float((unsigned int)h << 16);
}

// ---------------- degree count ----------------
__global__ __launch_bounds__(256) void k_deg(const int* __restrict__ dst, int* __restrict__ degcnt) {
    int e = blockIdx.x * 256 + threadIdx.x;
    if (e < NE) atomicAdd(&degcnt[dst[e]], 1);
}

__global__ __launch_bounds__(256) void k_dinv(const int* __restrict__ degcnt, float* __restrict__ dinv) {
    int i = blockIdx.x * 256 + threadIdx.x;
    if (i < NN) dinv[i] = (float)(1.0 / sqrt((double)degcnt[i] + 1.0));
}

// ---------------- prefix scan (3 stages) ----------------
__global__ __launch_bounds__(1024) void k_scan1(const int* __restrict__ cnt, int* __restrict__ row_ptr,
                                                int* __restrict__ blk_sums) {
    __shared__ int s[1024];
    const int tid = threadIdx.x;
    const int i = blockIdx.x * 1024 + tid;
    int v = (i < NN) ? cnt[i] : 0;
    s[tid] = v;
    __syncthreads();
    for (int off = 1; off < 1024; off <<= 1) {
        int t = (tid >= off) ? s[tid - off] : 0;
        __syncthreads();
        s[tid] += t;
        __syncthreads();
    }
    if (i < NN) row_ptr[i] = s[tid] - v;     // exclusive
    if (tid == 1023) blk_sums[blockIdx.x] = s[1023];
}

__global__ __launch_bounds__(64) void k_scan2(int* __restrict__ blk_sums, int nb) {
    int l = threadIdx.x;
    int v = (l < nb) ? blk_sums[l] : 0;
    int incl = v;
    for (int off = 1; off < 64; off <<= 1) {
        int t = __shfl_up(incl, off, 64);
        if (l >= off) incl += t;
    }
    if (l < nb) blk_sums[l] = incl - v;      // exclusive block offsets
}

__global__ __launch_bounds__(1024) void k_scan3(int* __restrict__ row_ptr, const int* __restrict__ blk_sums) {
    int i = blockIdx.x * 1024 + threadIdx.x;
    if (i < NN) row_ptr[i] += blk_sums[blockIdx.x];
    if (i == 0) row_ptr[NN] = NE;
}

// ---------------- CSR fill: src index only (4B/edge, 3.2MB scatter -> L2-resident) ----------------
__global__ __launch_bounds__(256) void k_fill(const int* __restrict__ ei, const int* __restrict__ row_ptr,
                                              int* __restrict__ cursor, int* __restrict__ csr_src) {
    int e = blockIdx.x * 256 + threadIdx.x;
    if (e >= NE) return;
    int s = ei[e];
    int d = ei[NE + e];
    int pos = row_ptr[d] + atomicAdd(&cursor[d], 1);
    csr_src[pos] = s;
}

// ---------------- bf16 MFMA GEMM: C[M x DO](bf16) = A[M x 128](f32) @ W[128 x DO](f32) ----------------
// m92-verified config: A row-major contiguous-8-K frags; B as N-major rows (Wt); C: col=lane&15,row=(lane>>4)*4+r
template <int DO>
__global__ __launch_bounds__(256) void k_gemm_mfma(const float* __restrict__ A, const float* __restrict__ W,
                                                   unsigned short* __restrict__ C, int M) {
    constexpr int NT = DO / 16;
    constexpr int LDK = 136;               // padded K stride in bf16 elems (272B rows: 16B-aligned, 2-way-free banks)
    __shared__ __align__(16) unsigned short As[64 * LDK];
    __shared__ __align__(16) unsigned short Wt[DO * LDK];
    const int tid = threadIdx.x;
    const int row0 = blockIdx.x * 64;

    // stage W transposed -> Wt[n][k] bf16
    for (int task = tid; task < 64 * (DO / 4); task += 256) {
        const int k0 = (task / (DO / 4)) * 2;
        const int n4 = (task % (DO / 4)) * 4;
        const float4 wa = *(const float4*)&W[(size_t)k0 * DO + n4];
        const float4 wb = *(const float4*)&W[(size_t)(k0 + 1) * DO + n4];
        const float pa[4] = {wa.x, wa.y, wa.z, wa.w};
        const float pb[4] = {wb.x, wb.y, wb.z, wb.w};
#pragma unroll
        for (int i = 0; i < 4; ++i) {
            const unsigned int pk = (unsigned int)f2bf(pa[i]) | ((unsigned int)f2bf(pb[i]) << 16);
            *(unsigned int*)&Wt[(n4 + i) * LDK + k0] = pk;
        }
    }
    // stage A tile -> As[row][k] bf16 (4 threads/row, 32 k each)
    {
        const int r = tid >> 2;
        const int ks = (tid & 3) * 32;
        const int grow = row0 + r;
#pragma unroll
        for (int q = 0; q < 8; ++q) {
            float4 v = make_float4(0.f, 0.f, 0.f, 0.f);
            if (grow < M) v = *(const float4*)&A[(size_t)grow * 128 + ks + q * 4];
            const unsigned long long pk =
                (unsigned long long)f2bf(v.x) | ((unsigned long long)f2bf(v.y) << 16) |
                ((unsigned long long)f2bf(v.z) << 32) | ((unsigned long long)f2bf(v.w) << 48);
            *(unsigned long long*)&As[r * LDK + ks + q * 4] = pk;
        }
    }
    __syncthreads();

    const int l = tid & 63;
    const int w = tid >> 6;
    const int lr = l & 15;                 // row-in-tile (A) / col (B,C)
    const int lg = l >> 4;                 // k-group (A,B) / row-group (C)
    f32x4 acc[NT];
#pragma unroll
    for (int nt = 0; nt < NT; ++nt) acc[nt] = (f32x4){0.f, 0.f, 0.f, 0.f};

#pragma unroll
    for (int kk = 0; kk < 128; kk += 32) {
        const short8 af = *(const short8*)&As[(w * 16 + lr) * LDK + kk + lg * 8];
#pragma unroll
        for (int nt = 0; nt < NT; ++nt) {
            const short8 bfv = *(const short8*)&Wt[(nt * 16 + lr) * LDK + kk + lg * 8];
            acc[nt] = __builtin_amdgcn_mfma_f32_16x16x32_bf16(af, bfv, acc[nt], 0, 0, 0);
        }
    }

#pragma unroll
    for (int nt = 0; nt < NT; ++nt) {
#pragma unroll
        for (int r = 0; r < 4; ++r) {
            const int grow = row0 + w * 16 + lg * 4 + r;
            if (grow < M) C[(size_t)grow * DO + nt * 16 + lr] = f2bf(acc[nt][r]);
        }
    }
}

// ---------------- aggregation: out = sum_e dinv[s]*dinv[n]*T[s] + dinv^2*T[n] + b (+relu) ----------------
template <int D, bool RELU>
__global__ __launch_bounds__(256) void k_agg(const unsigned short* __restrict__ T, const float* __restrict__ bias,
                                             const float* __restrict__ dinv, const int* __restrict__ row_ptr,
                                             const int* __restrict__ csr_src,
                                             float* __restrict__ out) {
    constexpr int G = D / 4;        // lanes per node, each lane owns 4 features (8 B bf16)
    constexpr int NPB = 256 / G;    // nodes per block
    const int tid = threadIdx.x;
    const int lane = tid % G;
    const int grp = tid / G;
    const int n = blockIdx.x * NPB + grp;
    if (n >= NN) return;

    const float di_n = dinv[n];
    double a0 = 0.0, a1 = 0.0, a2 = 0.0, a3 = 0.0;
    const int beg = row_ptr[n];
    const int end = row_ptr[n + 1];
    int e = beg;
    for (; e + 4 <= end; e += 4) {
        const int s0 = csr_src[e + 0], s1 = csr_src[e + 1], s2 = csr_src[e + 2], s3 = csr_src[e + 3];
        const float w0 = dinv[s0] * di_n, w1 = dinv[s1] * di_n, w2 = dinv[s2] * di_n, w3 = dinv[s3] * di_n;
        const ushort4 v0 = *(const ushort4*)&T[(size_t)s0 * D + lane * 4];
        const ushort4 v1 = *(const ushort4*)&T[(size_t)s1 * D + lane * 4];
        const ushort4 v2 = *(const ushort4*)&T[(size_t)s2 * D + lane * 4];
        const ushort4 v3 = *(const ushort4*)&T[(size_t)s3 * D + lane * 4];
        a0 += (double)w0 * bf2f(v0.x) + (double)w1 * bf2f(v1.x) + (double)w2 * bf2f(v2.x) + (double)w3 * bf2f(v3.x);
        a1 += (double)w0 * bf2f(v0.y) + (double)w1 * bf2f(v1.y) + (double)w2 * bf2f(v2.y) + (double)w3 * bf2f(v3.y);
        a2 += (double)w0 * bf2f(v0.z) + (double)w1 * bf2f(v1.z) + (double)w2 * bf2f(v2.z) + (double)w3 * bf2f(v3.z);
        a3 += (double)w0 * bf2f(v0.w) + (double)w1 * bf2f(v1.w) + (double)w2 * bf2f(v2.w) + (double)w3 * bf2f(v3.w);
    }
    for (; e < end; ++e) {
        const int s = csr_src[e];
        const float w = dinv[s] * di_n;
        const ushort4 v = *(const ushort4*)&T[(size_t)s * D + lane * 4];
        a0 += (double)w * bf2f(v.x);
        a1 += (double)w * bf2f(v.y);
        a2 += (double)w * bf2f(v.z);
        a3 += (double)w * bf2f(v.w);
    }
    // self-loop
    {
        const double w = (double)di_n * (double)di_n;
        const ushort4 v = *(const ushort4*)&T[(size_t)n * D + lane * 4];
        a0 += w * bf2f(v.x);
        a1 += w * bf2f(v.y);
        a2 += w * bf2f(v.z);
        a3 += w * bf2f(v.w);
    }
    // bias
    const float4 b = *(const float4*)&bias[lane * 4];
    a0 += b.x; a1 += b.y; a2 += b.z; a3 += b.w;
    float4 r;
    r.x = (float)a0; r.y = (float)a1; r.z = (float)a2; r.w = (float)a3;
    if (RELU) {
        r.x = fmaxf(r.x, 0.f);
        r.y = fmaxf(r.y, 0.f);
        r.z = fmaxf(r.z, 0.f);
        r.w = fmaxf(r.w, 0.f);
    }
    *(float4*)&out[(size_t)n * D + lane * 4] = r;
}

// ---------------- mean pool (batch sorted), f64 accum ----------------
__global__ __launch_bounds__(256) void k_pool(const float* __restrict__ h, const int* __restrict__ batch,
                                              double* __restrict__ sums, int* __restrict__ cnts) {
    const int NB = 256;
    const int n0 = blockIdx.x * NB;
    const int d = threadIdx.x & 63;
    const int sub = threadIdx.x >> 6;
    double acc = 0.0;
    int cnt = 0;
    int cur = -1;
    for (int i = sub; i < NB; i += 4) {
        int n = n0 + i;
        if (n >= NN) break;
        int g = batch[n];
        if (g != cur) {
            if (cur >= 0) {
                atomicAdd(&sums[cur * 64 + d], acc);
                if (d == 0) atomicAdd(&cnts[cur], cnt);
            }
            cur = g;
            acc = 0.0;
            cnt = 0;
        }
        acc += (double)h[(size_t)n * 64 + d];
        cnt++;
    }
    if (cur >= 0) {
        atomicAdd(&sums[cur * 64 + d], acc);
        if (d == 0) atomicAdd(&cnts[cur], cnt);
    }
}

__global__ __launch_bounds__(256) void k_final(const double* __restrict__ sums, const int* __restrict__ cnts,
                                               float* __restrict__ out) {
    int i = blockIdx.x * 256 + threadIdx.x;
    if (i >= NG * 64) return;
    int g = i >> 6;
    double c = (double)max(cnts[g], 1);
    out[i] = (float)(sums[i] / c);
}

extern "C" void kernel_launch(void* const* d_in, const int* in_sizes, int n_in,
                              void* d_out, int out_size, void* d_ws, size_t ws_size,
                              hipStream_t stream) {
    (void)in_sizes; (void)n_in; (void)out_size; (void)ws_size;
    const float* x     = (const float*)d_in[0];
    const int*   ei    = (const int*)d_in[1];
    const int*   batch = (const int*)d_in[2];
    const float* W1    = (const float*)d_in[3];
    const float* b1    = (const float*)d_in[4];
    const float* W2    = (const float*)d_in[5];
    const float* b2    = (const float*)d_in[6];
    const float* W3    = (const float*)d_in[7];
    const float* b3    = (const float*)d_in[8];
    float* out = (float*)d_out;

    // workspace layout: small metadata first, big h-buffers last
    char* w = (char*)d_ws;
    // zeroed region (single memset): degcnt | cursor | pool_sums(double) | pool_cnt
    char*  zbase = w;
    int*    degcnt = (int*)w;           w += (size_t)NN * 4;
    int*    cursor = (int*)w;           w += (size_t)NN * 4;
    double* psums  = (double*)w;        w += (size_t)NG * 64 * 8;
    int*    pcnts  = (int*)w;           w += 256;               // NG*4 padded to 16B
    size_t zbytes = (size_t)(w - zbase);
    float* dinv     = (float*)w;        w += (size_t)NN * 4;
    int*   row_ptr  = (int*)w;          w += (size_t)(NN + 4) * 4;
    int*   blk_sums = (int*)w;          w += 64 * 4;
    int*   csr_src  = (int*)w;          w += (size_t)NE * 4;
    unsigned short* bufT = (unsigned short*)w;  w += (size_t)NN * 128 * 2;  // bf16 gather target
    float* bufA = (float*)w;            w += (size_t)NN * 128 * 4;          // fp32 GEMM input

    hipMemsetAsync(zbase, 0, zbytes, stream);

    const int nb_scan = (NN + 1023) / 1024;   // 49
    k_deg<<<(NE + 255) / 256, 256, 0, stream>>>(ei + NE, degcnt);
    k_dinv<<<(NN + 255) / 256, 256, 0, stream>>>(degcnt, dinv);
    k_scan1<<<nb_scan, 1024, 0, stream>>>(degcnt, row_ptr, blk_sums);
    k_scan2<<<1, 64, 0, stream>>>(blk_sums, nb_scan);
    k_scan3<<<nb_scan, 1024, 0, stream>>>(row_ptr, blk_sums);
    k_fill<<<(NE + 255) / 256, 256, 0, stream>>>(ei, row_ptr, cursor, csr_src);

    const int gemm_grid = (NN + 63) / 64;     // 782
    // layer 1
    k_gemm_mfma<128><<<gemm_grid, 256, 0, stream>>>(x, W1, bufT, NN);
    k_agg<128, true><<<(NN + 7) / 8, 256, 0, stream>>>(bufT, b1, dinv, row_ptr, csr_src, bufA);
    // layer 2
    k_gemm_mfma<128><<<gemm_grid, 256, 0, stream>>>(bufA, W2, bufT, NN);
    k_agg<128, true><<<(NN + 7) / 8, 256, 0, stream>>>(bufT, b2, dinv, row_ptr, csr_src, bufA);
    // layer 3 (no relu, D_OUT=64)
    k_gemm_mfma<64><<<gemm_grid, 256, 0, stream>>>(bufA, W3, bufT, NN);
    k_agg<64, false><<<(NN + 15) / 16, 256, 0, stream>>>(bufT, b3, dinv, row_ptr, csr_src, bufA);
    // pool
    k_pool<<<(NN + 255) / 256, 256, 0, stream>>>(bufA, batch, psums, pcnts);
    k_final<<<(NG * 64 + 255) / 256, 256, 0, stream>>>(psums, pcnts, out);
}

// Round 7
// 252.818 us; speedup vs baseline: 1.5958x; 1.1756x over previous
//
#include <hip/hip_runtime.h>

#define NN 50000
#define NE 800000
#define NG 64
#define NCHUNK 64
#define CHUNK 12500     // NE / NCHUNK
#define HALF 25000      // NN / 2

typedef short short8 __attribute__((ext_vector_type(8)));
typedef float f32x4 __attribute__((ext_vector_type(4)));

// bf16 helpers (RTNE)
__device__ __forceinline__ unsigned short f2bf(float f) {
    unsigned int u = __float_as_uint(f);
    u = (u + 0x7FFFu + ((u >> 16) & 1u)) >> 16;
    return (unsigned short)u;
}
__device__ __forceinline__ float bf2f(unsigned short h) {
    return __uint_as_float((unsigned int)h << 16);
}

// ---------------- chunk histogram via LDS (packed 2x16-bit counters) ----------------
// grid (NCHUNK, 2): block (b,h) counts chunk b's edges whose dst is in half h.
// rank[e] = arrival order of e within (chunk, dst). percnt[b][d] = count.
__global__ __launch_bounds__(1024) void k_hist(const int* __restrict__ ei,
                                               unsigned short* __restrict__ rank,
                                               unsigned short* __restrict__ percnt) {
    __shared__ unsigned int cnt[HALF / 2];          // 50 KB: 2 ushort counters per word
    const int b = blockIdx.x;
    const int dbase = blockIdx.y * HALF;
    const int tid = threadIdx.x;
    for (int i = tid; i < HALF / 2; i += 1024) cnt[i] = 0;
    __syncthreads();
    const int e0 = b * CHUNK;
    for (int i = tid; i < CHUNK; i += 1024) {
        const int d = ei[NE + e0 + i];
        const int local = d - dbase;
        if ((unsigned)local < (unsigned)HALF) {
            const unsigned int old = atomicAdd(&cnt[local >> 1], 1u << ((local & 1) * 16));
            rank[e0 + i] = (unsigned short)((old >> ((local & 1) * 16)) & 0xFFFFu);
        }
    }
    __syncthreads();
    // dump cnt -> percnt[b][dbase .. dbase+HALF)
    unsigned int* dst = (unsigned int*)&percnt[(size_t)b * NN + dbase];
    for (int i = tid; i < HALF / 2; i += 1024) dst[i] = cnt[i];
}

// ---------------- per-dst exclusive scan over chunks (in-place) + degcnt ----------------
__global__ __launch_bounds__(256) void k_colscan(unsigned short* __restrict__ percnt,
                                                 int* __restrict__ degcnt) {
    const int d = blockIdx.x * 256 + threadIdx.x;
    if (d >= NN) return;
    int acc = 0;
#pragma unroll 8
    for (int b = 0; b < NCHUNK; ++b) {
        const int c = percnt[(size_t)b * NN + d];
        percnt[(size_t)b * NN + d] = (unsigned short)acc;   // exclusive prefix (fits: <= deg(d) < 65536)
        acc += c;
    }
    degcnt[d] = acc;
}

__global__ __launch_bounds__(256) void k_dinv(const int* __restrict__ degcnt, float* __restrict__ dinv) {
    int i = blockIdx.x * 256 + threadIdx.x;
    if (i < NN) dinv[i] = (float)(1.0 / sqrt((double)degcnt[i] + 1.0));
}

// ---------------- prefix scan (3 stages) ----------------
__global__ __launch_bounds__(1024) void k_scan1(const int* __restrict__ cnt, int* __restrict__ row_ptr,
                                                int* __restrict__ blk_sums) {
    __shared__ int s[1024];
    const int tid = threadIdx.x;
    const int i = blockIdx.x * 1024 + tid;
    int v = (i < NN) ? cnt[i] : 0;
    s[tid] = v;
    __syncthreads();
    for (int off = 1; off < 1024; off <<= 1) {
        int t = (tid >= off) ? s[tid - off] : 0;
        __syncthreads();
        s[tid] += t;
        __syncthreads();
    }
    if (i < NN) row_ptr[i] = s[tid] - v;     // exclusive
    if (tid == 1023) blk_sums[blockIdx.x] = s[1023];
}

__global__ __launch_bounds__(64) void k_scan2(int* __restrict__ blk_sums, int nb) {
    int l = threadIdx.x;
    int v = (l < nb) ? blk_sums[l] : 0;
    int incl = v;
    for (int off = 1; off < 64; off <<= 1) {
        int t = __shfl_up(incl, off, 64);
        if (l >= off) incl += t;
    }
    if (l < nb) blk_sums[l] = incl - v;      // exclusive block offsets
}

__global__ __launch_bounds__(1024) void k_scan3(int* __restrict__ row_ptr, const int* __restrict__ blk_sums) {
    int i = blockIdx.x * 1024 + threadIdx.x;
    if (i < NN) row_ptr[i] += blk_sums[blockIdx.x];
    if (i == 0) row_ptr[NN] = NE;
}

// ---------------- CSR fill: atomic-free ----------------
__global__ __launch_bounds__(256) void k_fill3(const int* __restrict__ ei, const int* __restrict__ row_ptr,
                                               const unsigned short* __restrict__ rank,
                                               const unsigned short* __restrict__ offs,
                                               int* __restrict__ csr_src) {
    const int e = blockIdx.x * 256 + threadIdx.x;
    if (e >= NE) return;
    const int s = ei[e];
    const int d = ei[NE + e];
    const int b = e / CHUNK;
    const int pos = row_ptr[d] + (int)offs[(size_t)b * NN + d] + (int)rank[e];
    csr_src[pos] = s;
}

// ---------------- bf16 MFMA GEMM: C[M x DO](bf16) = A[M x 128](f32) @ W[128 x DO](f32) ----------------
template <int DO>
__global__ __launch_bounds__(256) void k_gemm_mfma(const float* __restrict__ A, const float* __restrict__ W,
                                                   unsigned short* __restrict__ C, int M) {
    constexpr int NT = DO / 16;
    constexpr int LDK = 136;               // padded K stride in bf16 elems
    __shared__ __align__(16) unsigned short As[64 * LDK];
    __shared__ __align__(16) unsigned short Wt[DO * LDK];
    const int tid = threadIdx.x;
    const int row0 = blockIdx.x * 64;

    // stage W transposed -> Wt[n][k] bf16
    for (int task = tid; task < 64 * (DO / 4); task += 256) {
        const int k0 = (task / (DO / 4)) * 2;
        const int n4 = (task % (DO / 4)) * 4;
        const float4 wa = *(const float4*)&W[(size_t)k0 * DO + n4];
        const float4 wb = *(const float4*)&W[(size_t)(k0 + 1) * DO + n4];
        const float pa[4] = {wa.x, wa.y, wa.z, wa.w};
        const float pb[4] = {wb.x, wb.y, wb.z, wb.w};
#pragma unroll
        for (int i = 0; i < 4; ++i) {
            const unsigned int pk = (unsigned int)f2bf(pa[i]) | ((unsigned int)f2bf(pb[i]) << 16);
            *(unsigned int*)&Wt[(n4 + i) * LDK + k0] = pk;
        }
    }
    // stage A tile -> As[row][k] bf16 (4 threads/row, 32 k each)
    {
        const int r = tid >> 2;
        const int ks = (tid & 3) * 32;
        const int grow = row0 + r;
#pragma unroll
        for (int q = 0; q < 8; ++q) {
            float4 v = make_float4(0.f, 0.f, 0.f, 0.f);
            if (grow < M) v = *(const float4*)&A[(size_t)grow * 128 + ks + q * 4];
            const unsigned long long pk =
                (unsigned long long)f2bf(v.x) | ((unsigned long long)f2bf(v.y) << 16) |
                ((unsigned long long)f2bf(v.z) << 32) | ((unsigned long long)f2bf(v.w) << 48);
            *(unsigned long long*)&As[r * LDK + ks + q * 4] = pk;
        }
    }
    __syncthreads();

    const int l = tid & 63;
    const int w = tid >> 6;
    const int lr = l & 15;
    const int lg = l >> 4;
    f32x4 acc[NT];
#pragma unroll
    for (int nt = 0; nt < NT; ++nt) acc[nt] = (f32x4){0.f, 0.f, 0.f, 0.f};

#pragma unroll
    for (int kk = 0; kk < 128; kk += 32) {
        const short8 af = *(const short8*)&As[(w * 16 + lr) * LDK + kk + lg * 8];
#pragma unroll
        for (int nt = 0; nt < NT; ++nt) {
            const short8 bfv = *(const short8*)&Wt[(nt * 16 + lr) * LDK + kk + lg * 8];
            acc[nt] = __builtin_amdgcn_mfma_f32_16x16x32_bf16(af, bfv, acc[nt], 0, 0, 0);
        }
    }

#pragma unroll
    for (int nt = 0; nt < NT; ++nt) {
#pragma unroll
        for (int r = 0; r < 4; ++r) {
            const int grow = row0 + w * 16 + lg * 4 + r;
            if (grow < M) C[(size_t)grow * DO + nt * 16 + lr] = f2bf(acc[nt][r]);
        }
    }
}

// ---------------- aggregation: out = sum_e dinv[s]*dinv[n]*T[s] + dinv^2*T[n] + b (+relu) ----------------
template <int D, bool RELU>
__global__ __launch_bounds__(256) void k_agg(const unsigned short* __restrict__ T, const float* __restrict__ bias,
                                             const float* __restrict__ dinv, const int* __restrict__ row_ptr,
                                             const int* __restrict__ csr_src,
                                             float* __restrict__ out) {
    constexpr int G = D / 4;
    constexpr int NPB = 256 / G;
    const int tid = threadIdx.x;
    const int lane = tid % G;
    const int grp = tid / G;
    const int n = blockIdx.x * NPB + grp;
    if (n >= NN) return;

    const float di_n = dinv[n];
    double a0 = 0.0, a1 = 0.0, a2 = 0.0, a3 = 0.0;
    const int beg = row_ptr[n];
    const int end = row_ptr[n + 1];
    int e = beg;
    for (; e + 4 <= end; e += 4) {
        const int s0 = csr_src[e + 0], s1 = csr_src[e + 1], s2 = csr_src[e + 2], s3 = csr_src[e + 3];
        const float w0 = dinv[s0] * di_n, w1 = dinv[s1] * di_n, w2 = dinv[s2] * di_n, w3 = dinv[s3] * di_n;
        const ushort4 v0 = *(const ushort4*)&T[(size_t)s0 * D + lane * 4];
        const ushort4 v1 = *(const ushort4*)&T[(size_t)s1 * D + lane * 4];
        const ushort4 v2 = *(const ushort4*)&T[(size_t)s2 * D + lane * 4];
        const ushort4 v3 = *(const ushort4*)&T[(size_t)s3 * D + lane * 4];
        a0 += (double)w0 * bf2f(v0.x) + (double)w1 * bf2f(v1.x) + (double)w2 * bf2f(v2.x) + (double)w3 * bf2f(v3.x);
        a1 += (double)w0 * bf2f(v0.y) + (double)w1 * bf2f(v1.y) + (double)w2 * bf2f(v2.y) + (double)w3 * bf2f(v3.y);
        a2 += (double)w0 * bf2f(v0.z) + (double)w1 * bf2f(v1.z) + (double)w2 * bf2f(v2.z) + (double)w3 * bf2f(v3.z);
        a3 += (double)w0 * bf2f(v0.w) + (double)w1 * bf2f(v1.w) + (double)w2 * bf2f(v2.w) + (double)w3 * bf2f(v3.w);
    }
    for (; e < end; ++e) {
        const int s = csr_src[e];
        const float w = dinv[s] * di_n;
        const ushort4 v = *(const ushort4*)&T[(size_t)s * D + lane * 4];
        a0 += (double)w * bf2f(v.x);
        a1 += (double)w * bf2f(v.y);
        a2 += (double)w * bf2f(v.z);
        a3 += (double)w * bf2f(v.w);
    }
    // self-loop
    {
        const double w = (double)di_n * (double)di_n;
        const ushort4 v = *(const ushort4*)&T[(size_t)n * D + lane * 4];
        a0 += w * bf2f(v.x);
        a1 += w * bf2f(v.y);
        a2 += w * bf2f(v.z);
        a3 += w * bf2f(v.w);
    }
    const float4 b = *(const float4*)&bias[lane * 4];
    a0 += b.x; a1 += b.y; a2 += b.z; a3 += b.w;
    float4 r;
    r.x = (float)a0; r.y = (float)a1; r.z = (float)a2; r.w = (float)a3;
    if (RELU) {
        r.x = fmaxf(r.x, 0.f);
        r.y = fmaxf(r.y, 0.f);
        r.z = fmaxf(r.z, 0.f);
        r.w = fmaxf(r.w, 0.f);
    }
    *(float4*)&out[(size_t)n * D + lane * 4] = r;
}

// ---------------- mean pool (batch sorted), f64 accum ----------------
__global__ __launch_bounds__(256) void k_pool(const float* __restrict__ h, const int* __restrict__ batch,
                                              double* __restrict__ sums, int* __restrict__ cnts) {
    const int NB = 256;
    const int n0 = blockIdx.x * NB;
    const int d = threadIdx.x & 63;
    const int sub = threadIdx.x >> 6;
    double acc = 0.0;
    int cnt = 0;
    int cur = -1;
    for (int i = sub; i < NB; i += 4) {
        int n = n0 + i;
        if (n >= NN) break;
        int g = batch[n];
        if (g != cur) {
            if (cur >= 0) {
                atomicAdd(&sums[cur * 64 + d], acc);
                if (d == 0) atomicAdd(&cnts[cur], cnt);
            }
            cur = g;
            acc = 0.0;
            cnt = 0;
        }
        acc += (double)h[(size_t)n * 64 + d];
        cnt++;
    }
    if (cur >= 0) {
        atomicAdd(&sums[cur * 64 + d], acc);
        if (d == 0) atomicAdd(&cnts[cur], cnt);
    }
}

__global__ __launch_bounds__(256) void k_final(const double* __restrict__ sums, const int* __restrict__ cnts,
                                               float* __restrict__ out) {
    int i = blockIdx.x * 256 + threadIdx.x;
    if (i >= NG * 64) return;
    int g = i >> 6;
    double c = (double)max(cnts[g], 1);
    out[i] = (float)(sums[i] / c);
}

extern "C" void kernel_launch(void* const* d_in, const int* in_sizes, int n_in,
                              void* d_out, int out_size, void* d_ws, size_t ws_size,
                              hipStream_t stream) {
    (void)in_sizes; (void)n_in; (void)out_size; (void)ws_size;
    const float* x     = (const float*)d_in[0];
    const int*   ei    = (const int*)d_in[1];
    const int*   batch = (const int*)d_in[2];
    const float* W1    = (const float*)d_in[3];
    const float* b1    = (const float*)d_in[4];
    const float* W2    = (const float*)d_in[5];
    const float* b2    = (const float*)d_in[6];
    const float* W3    = (const float*)d_in[7];
    const float* b3    = (const float*)d_in[8];
    float* out = (float*)d_out;

    // workspace layout
    char* w = (char*)d_ws;
    // zeroed region: pool sums + counts only
    char*  zbase = w;
    double* psums  = (double*)w;        w += (size_t)NG * 64 * 8;
    int*    pcnts  = (int*)w;           w += 256;
    size_t zbytes = (size_t)(w - zbase);
    int*    degcnt = (int*)w;           w += (size_t)NN * 4;       // written by colscan, no zeroing
    float*  dinv   = (float*)w;         w += (size_t)NN * 4;
    int*    row_ptr = (int*)w;          w += (size_t)(NN + 4) * 4;
    int*    blk_sums = (int*)w;         w += 64 * 4;
    unsigned short* rank   = (unsigned short*)w;  w += (size_t)NE * 2;          // 1.6 MB
    unsigned short* percnt = (unsigned short*)w;  w += (size_t)NCHUNK * NN * 2; // 6.4 MB (becomes offs in-place)
    int*    csr_src = (int*)w;          w += (size_t)NE * 4;
    unsigned short* bufT = (unsigned short*)w;  w += (size_t)NN * 128 * 2;  // bf16 gather target
    float* bufA = (float*)w;            w += (size_t)NN * 128 * 4;          // fp32 GEMM input

    hipMemsetAsync(zbase, 0, zbytes, stream);

    // atomic-free CSR build
    k_hist<<<dim3(NCHUNK, 2), 1024, 0, stream>>>(ei, rank, percnt);
    k_colscan<<<(NN + 255) / 256, 256, 0, stream>>>(percnt, degcnt);
    k_dinv<<<(NN + 255) / 256, 256, 0, stream>>>(degcnt, dinv);
    const int nb_scan = (NN + 1023) / 1024;   // 49
    k_scan1<<<nb_scan, 1024, 0, stream>>>(degcnt, row_ptr, blk_sums);
    k_scan2<<<1, 64, 0, stream>>>(blk_sums, nb_scan);
    k_scan3<<<nb_scan, 1024, 0, stream>>>(row_ptr, blk_sums);
    k_fill3<<<(NE + 255) / 256, 256, 0, stream>>>(ei, row_ptr, rank, percnt, csr_src);

    const int gemm_grid = (NN + 63) / 64;     // 782
    // layer 1
    k_gemm_mfma<128><<<gemm_grid, 256, 0, stream>>>(x, W1, bufT, NN);
    k_agg<128, true><<<(NN + 7) / 8, 256, 0, stream>>>(bufT, b1, dinv, row_ptr, csr_src, bufA);
    // layer 2
    k_gemm_mfma<128><<<gemm_grid, 256, 0, stream>>>(bufA, W2, bufT, NN);
    k_agg<128, true><<<(NN + 7) / 8, 256, 0, stream>>>(bufT, b2, dinv, row_ptr, csr_src, bufA);
    // layer 3 (no relu, D_OUT=64)
    k_gemm_mfma<64><<<gemm_grid, 256, 0, stream>>>(bufA, W3, bufT, NN);
    k_agg<64, false><<<(NN + 15) / 16, 256, 0, stream>>>(bufT, b3, dinv, row_ptr, csr_src, bufA);
    // pool
    k_pool<<<(NN + 255) / 256, 256, 0, stream>>>(bufA, batch, psums, pcnts);
    k_final<<<(NG * 64 + 255) / 256, 256, 0, stream>>>(psums, pcnts, out);
}